// Round 10
// baseline (904.538 us; speedup 1.0000x reference)
//
#include <hip/hip_runtime.h>
#include <stdint.h>

// N=8192 samples, D=4096 statevector dim (fixed by reference)
#define NN 8192
#define DD 4096
#define BK 64           // K-step (one i8 MFMA covers K=64)
#define NT (DD / BK)    // 64 K-steps
#define BM 64           // tile rows (A)
#define BN 128          // tile cols (B)
#define LDS_B 16384     // B tile: 128 rows x 128 B (re[64]|im[64] i8, 8-slot XOR swizzle)
#define NTILE 4160      // staircase: sum_{bj=0}^{63} (2bj+2) = 64*65

// Packed operand layout (MFMA-ready, written by convert):
//   offset(rb, kc, part, fr) = ((rb*256 + kc)*3 + part)*256 + fr*16
//   rb = row>>4 (512), kc = k-chunk of 16 i8 (256), part: 0=re 1=im 2=-re, fr = row&15.
// Total 96 MB in d_ws. A-fragments read coalesced (256B runs) direct to VGPR;
// B staged to LDS from the re/im parts (same logical bytes as rounds 8/9).

typedef int   i32x4 __attribute__((ext_vector_type(4)));
typedef float f32x4 __attribute__((ext_vector_type(4)));

#define GLOAD(g, l) __builtin_amdgcn_global_load_lds( \
    (__attribute__((address_space(1))) uint32_t*)(void*)(size_t)(g), \
    (__attribute__((address_space(3))) uint32_t*)(void*)(l), 16, 0, 0)

#define VMW4() asm volatile("s_waitcnt vmcnt(4)" ::: "memory")
#define VMW0() asm volatile("s_waitcnt vmcnt(0)" ::: "memory")
#define SBAR() __builtin_amdgcn_s_barrier()

#define MFMA_I8(a, b, c) __builtin_amdgcn_mfma_i32_16x16x64_i8((a), (b), (c), 0, 0, 0)

// fp32 -> per-row-scaled int8, written in packed MFMA-ready layout (re, im, -re).
__global__ __launch_bounds__(256) void convert_kernel(
    const float* __restrict__ re, const float* __restrict__ im,
    char* __restrict__ apk, float* __restrict__ scales) {
  __shared__ float red[4];
  const int row = blockIdx.x;
  const int t = threadIdx.x;
  const int rb = row >> 4, fr = row & 15;
  const float4* rr = (const float4*)(re + (size_t)row * DD);
  const float4* ir = (const float4*)(im + (size_t)row * DD);
  float4 rv[4], iv[4];
  float mx = 0.f;
#pragma unroll
  for (int c = 0; c < 4; ++c) {
    rv[c] = rr[t * 4 + c];
    iv[c] = ir[t * 4 + c];
    mx = fmaxf(mx, fmaxf(fmaxf(fabsf(rv[c].x), fabsf(rv[c].y)),
                         fmaxf(fabsf(rv[c].z), fabsf(rv[c].w))));
    mx = fmaxf(mx, fmaxf(fmaxf(fabsf(iv[c].x), fabsf(iv[c].y)),
                         fmaxf(fabsf(iv[c].z), fabsf(iv[c].w))));
  }
#pragma unroll
  for (int off = 32; off > 0; off >>= 1) mx = fmaxf(mx, __shfl_down(mx, off));
  if ((t & 63) == 0) red[t >> 6] = mx;
  __syncthreads();
  mx = fmaxf(fmaxf(red[0], red[1]), fmaxf(red[2], red[3]));
  const float inv = (mx > 1e-30f) ? (127.0f / mx) : 0.0f;
  if (t == 0) scales[row] = mx * (1.0f / 127.0f);

  i32x4 rp, ip, np;
#pragma unroll
  for (int c = 0; c < 4; ++c) {
    int b0 = (int)rintf(rv[c].x * inv), b1 = (int)rintf(rv[c].y * inv);
    int b2 = (int)rintf(rv[c].z * inv), b3 = (int)rintf(rv[c].w * inv);
    rp[c] = (b0 & 0xFF) | ((b1 & 0xFF) << 8) | ((b2 & 0xFF) << 16) | (b3 << 24);
    np[c] = ((-b0) & 0xFF) | (((-b1) & 0xFF) << 8) | (((-b2) & 0xFF) << 16) | ((-b3) << 24);
    b0 = (int)rintf(iv[c].x * inv); b1 = (int)rintf(iv[c].y * inv);
    b2 = (int)rintf(iv[c].z * inv); b3 = (int)rintf(iv[c].w * inv);
    ip[c] = (b0 & 0xFF) | ((b1 & 0xFF) << 8) | ((b2 & 0xFF) << 16) | (b3 << 24);
  }
  // thread t owns k-chunk kc = t of this row
  char* base = apk + ((size_t)rb * 256 + t) * 768 + (size_t)fr * 16;
  *(i32x4*)(base)       = rp;   // part 0: re
  *(i32x4*)(base + 256) = ip;   // part 1: im
  *(i32x4*)(base + 512) = np;   // part 2: -re
}

// 64x128 tile of G per (bi, bj), bi <= 2bj+1 staircase (covers upper triangle).
// acc_g = re.re' + im.im'; acc_i = im.re' + (-re).im' = g_im (2 accs, 64 regs).
// A fragments: coalesced global loads direct to VGPR from packed (no LDS).
// B: LDS-staged, XOR-swizzled (verified conflict-free rounds 8/9). 3 blocks/CU.
__global__ __launch_bounds__(256, 3) void gram_kernel(
    const char* __restrict__ apk, const float* __restrict__ scales,
    float* __restrict__ wts, float* __restrict__ fidp) {
  __shared__ alignas(16) char lds[2 * LDS_B];  // 32 KB

  // XCD-aware bijective swizzle (4160 = 8*520)
  const int b = blockIdx.x;
  const int t = (b & 7) * 520 + (b >> 3);

  // staircase: C(bj) = bj*(bj+1); bj s.t. C(bj) <= t < C(bj+1); bi = t - C(bj)
  int bj = (int)((sqrtf((float)(4 * t + 1)) - 1.0f) * 0.5f);
  if (bj < 0) bj = 0;
  if (bj > 63) bj = 63;
  while (bj > 0 && t < bj * (bj + 1)) --bj;
  while (t >= (bj + 1) * (bj + 2)) ++bj;
  const int bi = t - bj * (bj + 1);

  const int brow = bi * BM, bcol = bj * BN;
  const int tid = threadIdx.x;
  const int lane = tid & 63;
  const int wid = tid >> 6;               // 4 waves
  const int wr = wid >> 1, wc = wid & 1;  // wave-tile 32 rows x 64 cols
  const int t16 = tid * 16;

  // ---- B staging from packed (pre-swizzled; LDS dest linear). LDS contents are
  // byte-identical to rounds 8/9: row r slot p holds logical slot p^(r&7);
  // logical 0-3 = re chunks, 4-7 = im chunks. ----
  const int srow = tid >> 3;                    // 0..31 (rounds add 32)
  const int slog = (tid & 7) ^ (srow & 7);
  const int part = slog >> 2;                   // 0=re, 1=im
  const int c4 = slog & 3;                      // chunk within K-step
  const int brr = bcol + srow;
  const char* spB = apk + (((size_t)(brr >> 4) * 256 + c4) * 3 + part) * 256
                        + (size_t)(brr & 15) * 16;
  // +32 rows => rb+2 => +2*256*768 = 393216 bytes; K-step s => +s*3072

#define STAGE_B(s, bf) do { const size_t ko = (size_t)(s) * 3072;  \
    char* lb_ = lds + (bf) * LDS_B + t16;                          \
    GLOAD(spB + ko,              lb_);                             \
    GLOAD(spB + ko + 393216,     lb_ + 4096);                      \
    GLOAD(spB + ko + 2 * 393216, lb_ + 8192);                      \
    GLOAD(spB + ko + 3 * 393216, lb_ + 12288); } while (0)

  // ---- A fragment global pointers (coalesced: quarter-wave = 256 B run) ----
  const int fr = lane & 15;
  const int kg = lane >> 4;
  const size_t a0 = ((size_t)((brow >> 4) + wr * 2) * 256 + kg) * 768 + (size_t)fr * 16;
  const char* gAr0 = apk + a0;            // m=0: re
  const char* gAi0 = gAr0 + 256;          //      im
  const char* gAn0 = gAr0 + 512;          //      -re
  const char* gAr1 = gAr0 + 196608;       // m=1 (rb+1 = +256*768)
  const char* gAi1 = gAr1 + 256;
  const char* gAn1 = gAr1 + 512;

  // ---- B fragment read offsets (verified: slot_phys = kg ^ (row&7)) ----
  const int reslot = (kg ^ (fr & 7)) << 4;   // re slot; im = ^64
  const int brw = (wc * 64 + fr) * 128;      // + n*2048

  i32x4 acc_g[2][4], acc_i[2][4];
#pragma unroll
  for (int m = 0; m < 2; ++m)
#pragma unroll
    for (int n = 0; n < 4; ++n) {
      acc_g[m][n] = (i32x4){0, 0, 0, 0};
      acc_i[m][n] = (i32x4){0, 0, 0, 0};
    }

  // ---- prologue ----
  STAGE_B(0, 0);
  VMW0();
  SBAR();

  for (int s = 0; s < NT; ++s) {
    const char* lb = lds + (s & 1) * LDS_B;
    const int nb = (s & 1) ^ 1;
    const bool pf = (s + 1 < NT);
    const size_t so = (size_t)s * 3072;

    // A(s) fragments -> VGPR (6 coalesced dwordx4), then B(s+1) staging (4 gloads)
    i32x4 ar0 = *(const i32x4*)(gAr0 + so);
    i32x4 ai0 = *(const i32x4*)(gAi0 + so);
    i32x4 an0 = *(const i32x4*)(gAn0 + so);
    i32x4 ar1 = *(const i32x4*)(gAr1 + so);
    i32x4 ai1 = *(const i32x4*)(gAi1 + so);
    i32x4 an1 = *(const i32x4*)(gAn1 + so);
    if (pf) { STAGE_B(s + 1, nb); VMW4(); }  // retire the 6 A loads, keep B in flight
    else    { VMW0(); }

#pragma unroll
    for (int n = 0; n < 4; ++n) {
      i32x4 brf = *(const i32x4*)(lb + brw + n * 2048 + reslot);
      i32x4 bif = *(const i32x4*)(lb + brw + n * 2048 + (reslot ^ 64));
      __builtin_amdgcn_s_setprio(1);
      acc_g[0][n] = MFMA_I8(ar0, brf, acc_g[0][n]);
      acc_g[0][n] = MFMA_I8(ai0, bif, acc_g[0][n]);
      acc_i[0][n] = MFMA_I8(ai0, brf, acc_i[0][n]);
      acc_i[0][n] = MFMA_I8(an0, bif, acc_i[0][n]);
      acc_g[1][n] = MFMA_I8(ar1, brf, acc_g[1][n]);
      acc_g[1][n] = MFMA_I8(ai1, bif, acc_g[1][n]);
      acc_i[1][n] = MFMA_I8(ai1, brf, acc_i[1][n]);
      acc_i[1][n] = MFMA_I8(an1, bif, acc_i[1][n]);
      __builtin_amdgcn_s_setprio(0);
    }

    if (pf) VMW0();   // B(s+1) landed (issued a full step earlier -> free)
    SBAR();
  }

  // ---- epilogue: 16x16 C/D layout (verified): col=lane&15, row=(lane>>4)*4+reg ----
  const int grow0 = brow + wr * 32 + kg * 4;  // + m*16 + j
  const int gcol0 = bcol + wc * 64 + fr;      // + n*16
  const bool fullUpper = (brow + BM) <= bcol; // tile entirely strictly-upper
  const f32x4 zz = {0.f, 0.f, 0.f, 0.f};

#pragma unroll
  for (int m = 0; m < 2; ++m) {
#pragma unroll
    for (int n = 0; n < 4; ++n) {
      const int gc = gcol0 + n * 16;
      const float sb = scales[gc];
      f32x4 fv;
#pragma unroll
      for (int j = 0; j < 4; ++j) {
        const int grow = grow0 + m * 16 + j;
        const float ss = scales[grow] * sb;
        const float gr = (float)acc_g[m][n][j] * ss;
        const float gi = (float)acc_i[m][n][j] * ss;
        fv[j] = gr * gr + gi * gi;
      }
#pragma unroll
      for (int j = 0; j < 4; ++j) {
        const int grow = grow0 + m * 16 + j;
        const float f = fv[j];
        fidp[(size_t)grow * NN + gc] = f;
        float w = 0.0f;
        if (grow < gc) w = (f >= 0.8f) ? 1.0f : ((f >= 0.5f) ? 0.5f : 0.0f);
        wts[(size_t)grow * NN + gc] = w;
      }
      // mirror: fid symmetric; mirror targets are strictly-lower -> wts = 0
      if (fullUpper) {
        *(f32x4*)(fidp + (size_t)gc * NN + grow0 + m * 16) = fv;
        *(f32x4*)(wts  + (size_t)gc * NN + grow0 + m * 16) = zz;
      } else {
#pragma unroll
        for (int j = 0; j < 4; ++j) {
          const int grow = grow0 + m * 16 + j;
          if (grow < gc) {
            fidp[(size_t)gc * NN + grow] = fv[j];
            wts[(size_t)gc * NN + grow] = 0.0f;
          }
        }
      }
    }
  }
}

extern "C" void kernel_launch(void* const* d_in, const int* in_sizes, int n_in,
                              void* d_out, int out_size, void* d_ws, size_t ws_size,
                              hipStream_t stream) {
  const float* re = (const float*)d_in[0];
  const float* im = (const float*)d_in[1];
  float* out = (float*)d_out;

  char* apk = (char*)d_ws;                                   // 96 MB packed operands
  float* scales = (float*)(apk + (size_t)512 * 256 * 768);   // N f32

  convert_kernel<<<NN, 256, 0, stream>>>(re, im, apk, scales);
  gram_kernel<<<NTILE, 256, 0, stream>>>(apk, scales, out, out + (size_t)NN * NN);
}

// Round 11
// 898.727 us; speedup vs baseline: 1.0065x; 1.0065x over previous
//
#include <hip/hip_runtime.h>
#include <stdint.h>

// N=8192 samples, D=4096 statevector dim (fixed by reference)
#define NN 8192
#define DD 4096
#define BK 64           // K-step (one i8 MFMA covers K=64)
#define NT (DD / BK)    // 64 K-steps
#define BM 64           // tile rows (A)
#define BN 128          // tile cols (B)
#define LDS_B 16384     // B tile: 128 rows x 128 B (re[64]|im[64] i8, 8-slot XOR swizzle)
#define NTILE 4160      // staircase: sum_{bj=0}^{63} (2bj+2) = 64*65

// Packed operand layout (MFMA-ready, written by convert):
//   offset(rb, kc, part, fr) = ((rb*256 + kc)*3 + part)*256 + fr*16
//   rb = row>>4 (512), kc = k-chunk of 16 i8 (256), part: 0=re 1=im 2=-re, fr = row&15.

typedef int   i32x4 __attribute__((ext_vector_type(4)));
typedef float f32x4 __attribute__((ext_vector_type(4)));

#define GLOAD(g, l) __builtin_amdgcn_global_load_lds( \
    (__attribute__((address_space(1))) uint32_t*)(void*)(size_t)(g), \
    (__attribute__((address_space(3))) uint32_t*)(void*)(l), 16, 0, 0)

#define VMW0() asm volatile("s_waitcnt vmcnt(0)" ::: "memory")
#define SBAR() __builtin_amdgcn_s_barrier()

#define MFMA_I8(a, b, c) __builtin_amdgcn_mfma_i32_16x16x64_i8((a), (b), (c), 0, 0, 0)

// fp32 -> per-row-scaled int8, packed MFMA-ready (re, im, -re). (unchanged r10)
__global__ __launch_bounds__(256) void convert_kernel(
    const float* __restrict__ re, const float* __restrict__ im,
    char* __restrict__ apk, float* __restrict__ scales) {
  __shared__ float red[4];
  const int row = blockIdx.x;
  const int t = threadIdx.x;
  const int rb = row >> 4, fr = row & 15;
  const float4* rr = (const float4*)(re + (size_t)row * DD);
  const float4* ir = (const float4*)(im + (size_t)row * DD);
  float4 rv[4], iv[4];
  float mx = 0.f;
#pragma unroll
  for (int c = 0; c < 4; ++c) {
    rv[c] = rr[t * 4 + c];
    iv[c] = ir[t * 4 + c];
    mx = fmaxf(mx, fmaxf(fmaxf(fabsf(rv[c].x), fabsf(rv[c].y)),
                         fmaxf(fabsf(rv[c].z), fabsf(rv[c].w))));
    mx = fmaxf(mx, fmaxf(fmaxf(fabsf(iv[c].x), fabsf(iv[c].y)),
                         fmaxf(fabsf(iv[c].z), fabsf(iv[c].w))));
  }
#pragma unroll
  for (int off = 32; off > 0; off >>= 1) mx = fmaxf(mx, __shfl_down(mx, off));
  if ((t & 63) == 0) red[t >> 6] = mx;
  __syncthreads();
  mx = fmaxf(fmaxf(red[0], red[1]), fmaxf(red[2], red[3]));
  const float inv = (mx > 1e-30f) ? (127.0f / mx) : 0.0f;
  if (t == 0) scales[row] = mx * (1.0f / 127.0f);

  i32x4 rp, ip, np;
#pragma unroll
  for (int c = 0; c < 4; ++c) {
    int b0 = (int)rintf(rv[c].x * inv), b1 = (int)rintf(rv[c].y * inv);
    int b2 = (int)rintf(rv[c].z * inv), b3 = (int)rintf(rv[c].w * inv);
    rp[c] = (b0 & 0xFF) | ((b1 & 0xFF) << 8) | ((b2 & 0xFF) << 16) | (b3 << 24);
    np[c] = ((-b0) & 0xFF) | (((-b1) & 0xFF) << 8) | (((-b2) & 0xFF) << 16) | ((-b3) << 24);
    b0 = (int)rintf(iv[c].x * inv); b1 = (int)rintf(iv[c].y * inv);
    b2 = (int)rintf(iv[c].z * inv); b3 = (int)rintf(iv[c].w * inv);
    ip[c] = (b0 & 0xFF) | ((b1 & 0xFF) << 8) | ((b2 & 0xFF) << 16) | (b3 << 24);
  }
  char* base = apk + ((size_t)rb * 256 + t) * 768 + (size_t)fr * 16;
  *(i32x4*)(base)       = rp;   // part 0: re
  *(i32x4*)(base + 256) = ip;   // part 1: im
  *(i32x4*)(base + 512) = np;   // part 2: -re
}

// 64x128 tile of G per (bi, bj), staircase bi <= 2bj+1 (covers upper triangle).
// acc_g = re.re' + im.im'; acc_i = im.re' + (-re).im' (2 accs).
// A fragments: coalesced global->VGPR, DOUBLE-BUFFERED ONE K-STEP AHEAD (fixes the
// round-10 unhidden A-load latency: loads now have a full MFMA phase to land).
// B: LDS-staged, XOR-swizzled (verified conflict-free). r8-proven 1-barrier loop.
__global__ __launch_bounds__(256, 3) void gram_kernel(
    const char* __restrict__ apk, const float* __restrict__ scales,
    float* __restrict__ wts, float* __restrict__ fidp) {
  __shared__ alignas(16) char lds[2 * LDS_B];  // 32 KB

  // XCD-aware bijective swizzle (4160 = 8*520)
  const int b = blockIdx.x;
  const int t = (b & 7) * 520 + (b >> 3);

  // staircase: C(bj) = bj*(bj+1); bj s.t. C(bj) <= t < C(bj+1); bi = t - C(bj)
  int bj = (int)((sqrtf((float)(4 * t + 1)) - 1.0f) * 0.5f);
  if (bj < 0) bj = 0;
  if (bj > 63) bj = 63;
  while (bj > 0 && t < bj * (bj + 1)) --bj;
  while (t >= (bj + 1) * (bj + 2)) ++bj;
  const int bi = t - bj * (bj + 1);

  const int brow = bi * BM, bcol = bj * BN;
  const int tid = threadIdx.x;
  const int lane = tid & 63;
  const int wid = tid >> 6;               // 4 waves
  const int wr = wid >> 1, wc = wid & 1;  // wave-tile 32 rows x 64 cols
  const int t16 = tid * 16;

  // ---- B staging from packed (pre-swizzled; LDS dest linear; bytes identical r8/r9) ----
  const int srow = tid >> 3;
  const int slog = (tid & 7) ^ (srow & 7);
  const int part = slog >> 2;                   // 0=re, 1=im
  const int c4 = slog & 3;
  const int brr = bcol + srow;
  const char* spB = apk + (((size_t)(brr >> 4) * 256 + c4) * 3 + part) * 256
                        + (size_t)(brr & 15) * 16;

#define STAGE_B(s, bf) do { const size_t ko = (size_t)(s) * 3072;  \
    char* lb_ = lds + (bf) * LDS_B + t16;                          \
    GLOAD(spB + ko,              lb_);                             \
    GLOAD(spB + ko + 393216,     lb_ + 4096);                      \
    GLOAD(spB + ko + 2 * 393216, lb_ + 8192);                      \
    GLOAD(spB + ko + 3 * 393216, lb_ + 12288); } while (0)

  // ---- A fragment global pointers (quarter-wave = 256 B coalesced run) ----
  const int fr = lane & 15;
  const int kg = lane >> 4;
  const size_t a0 = ((size_t)((brow >> 4) + wr * 2) * 256 + kg) * 768 + (size_t)fr * 16;
  const char* gAr0 = apk + a0;
  const char* gAi0 = gAr0 + 256;
  const char* gAn0 = gAr0 + 512;
  const char* gAr1 = gAr0 + 196608;   // rb+1
  const char* gAi1 = gAr1 + 256;
  const char* gAn1 = gAr1 + 512;

  // ---- B fragment read offsets (verified: slot_phys = kg ^ (row&7)) ----
  const int reslot = (kg ^ (fr & 7)) << 4;
  const int brw = (wc * 64 + fr) * 128;

  i32x4 acc_g[2][4], acc_i[2][4];
#pragma unroll
  for (int m = 0; m < 2; ++m)
#pragma unroll
    for (int n = 0; n < 4; ++n) {
      acc_g[m][n] = (i32x4){0, 0, 0, 0};
      acc_i[m][n] = (i32x4){0, 0, 0, 0};
    }

  // two named A-register sets (static indexing, rule #20)
  i32x4 X_r0, X_i0, X_n0, X_r1, X_i1, X_n1;
  i32x4 Y_r0, Y_i0, Y_n0, Y_r1, Y_i1, Y_n1;

#define ASET_LOAD(SET, s) do { const size_t so_ = (size_t)(s) * 3072;   \
    SET##_r0 = *(const i32x4*)(gAr0 + so_);                             \
    SET##_i0 = *(const i32x4*)(gAi0 + so_);                             \
    SET##_n0 = *(const i32x4*)(gAn0 + so_);                             \
    SET##_r1 = *(const i32x4*)(gAr1 + so_);                             \
    SET##_i1 = *(const i32x4*)(gAi1 + so_);                             \
    SET##_n1 = *(const i32x4*)(gAn1 + so_); } while (0)

#define MFMA8S(SET, n, brf, bif) do {                          \
    acc_g[0][n] = MFMA_I8(SET##_r0, brf, acc_g[0][n]);         \
    acc_g[0][n] = MFMA_I8(SET##_i0, bif, acc_g[0][n]);         \
    acc_i[0][n] = MFMA_I8(SET##_i0, brf, acc_i[0][n]);         \
    acc_i[0][n] = MFMA_I8(SET##_n0, bif, acc_i[0][n]);         \
    acc_g[1][n] = MFMA_I8(SET##_r1, brf, acc_g[1][n]);         \
    acc_g[1][n] = MFMA_I8(SET##_i1, bif, acc_g[1][n]);         \
    acc_i[1][n] = MFMA_I8(SET##_i1, brf, acc_i[1][n]);         \
    acc_i[1][n] = MFMA_I8(SET##_n1, bif, acc_i[1][n]);         \
  } while (0)

  // STEP: issue A(s+1)->NXT + STAGE_B(s+1) first (full MFMA phase to land),
  // compute with CUR + B(s) from LDS, drain, barrier.
#define STEP(CUR, NXT, s) do {                                              \
    const char* lb = lds + ((s) & 1) * LDS_B;                               \
    if ((s) + 1 < NT) { ASET_LOAD(NXT, (s) + 1);                            \
                        STAGE_B((s) + 1, ((s) + 1) & 1); }                  \
    _Pragma("unroll") for (int n = 0; n < 4; ++n) {                         \
      i32x4 brf = *(const i32x4*)(lb + brw + n * 2048 + reslot);            \
      i32x4 bif = *(const i32x4*)(lb + brw + n * 2048 + (reslot ^ 64));     \
      __builtin_amdgcn_s_setprio(1);                                        \
      MFMA8S(CUR, n, brf, bif);                                             \
      __builtin_amdgcn_s_setprio(0);                                        \
    }                                                                       \
    VMW0();                                                                 \
    SBAR();                                                                 \
  } while (0)

  // ---- prologue: A(0) -> X, stage B(0), drain ----
  ASET_LOAD(X, 0);
  STAGE_B(0, 0);
  VMW0();
  SBAR();

  for (int s = 0; s < NT; s += 2) {
    STEP(X, Y, s);
    STEP(Y, X, s + 1);
  }

  // ---- epilogue: 16x16 C/D layout (verified): col=lane&15, row=(lane>>4)*4+reg ----
  const int grow0 = brow + wr * 32 + kg * 4;  // + m*16 + j
  const int gcol0 = bcol + wc * 64 + fr;      // + n*16
  const bool fullUpper = (brow + BM) <= bcol;
  const f32x4 zz = {0.f, 0.f, 0.f, 0.f};

#pragma unroll
  for (int m = 0; m < 2; ++m) {
#pragma unroll
    for (int n = 0; n < 4; ++n) {
      const int gc = gcol0 + n * 16;
      const float sb = scales[gc];
      f32x4 fv;
#pragma unroll
      for (int j = 0; j < 4; ++j) {
        const int grow = grow0 + m * 16 + j;
        const float ss = scales[grow] * sb;
        const float gr = (float)acc_g[m][n][j] * ss;
        const float gi = (float)acc_i[m][n][j] * ss;
        fv[j] = gr * gr + gi * gi;
      }
#pragma unroll
      for (int j = 0; j < 4; ++j) {
        const int grow = grow0 + m * 16 + j;
        const float f = fv[j];
        fidp[(size_t)grow * NN + gc] = f;
        float w = 0.0f;
        if (grow < gc) w = (f >= 0.8f) ? 1.0f : ((f >= 0.5f) ? 0.5f : 0.0f);
        wts[(size_t)grow * NN + gc] = w;
      }
      // mirror: fid symmetric; mirror targets strictly-lower -> wts = 0
      if (fullUpper) {
        *(f32x4*)(fidp + (size_t)gc * NN + grow0 + m * 16) = fv;
        *(f32x4*)(wts  + (size_t)gc * NN + grow0 + m * 16) = zz;
      } else {
#pragma unroll
        for (int j = 0; j < 4; ++j) {
          const int grow = grow0 + m * 16 + j;
          if (grow < gc) {
            fidp[(size_t)gc * NN + grow] = fv[j];
            wts[(size_t)gc * NN + grow] = 0.0f;
          }
        }
      }
    }
  }
}

extern "C" void kernel_launch(void* const* d_in, const int* in_sizes, int n_in,
                              void* d_out, int out_size, void* d_ws, size_t ws_size,
                              hipStream_t stream) {
  const float* re = (const float*)d_in[0];
  const float* im = (const float*)d_in[1];
  float* out = (float*)d_out;

  char* apk = (char*)d_ws;                                   // 96 MB packed operands
  float* scales = (float*)(apk + (size_t)512 * 256 * 768);   // N f32

  convert_kernel<<<NN, 256, 0, stream>>>(re, im, apk, scales);
  gram_kernel<<<NTILE, 256, 0, stream>>>(apk, scales, out, out + (size_t)NN * NN);
}

// Round 12
// 605.780 us; speedup vs baseline: 1.4932x; 1.4836x over previous
//
#include <hip/hip_runtime.h>
#include <stdint.h>

// N=8192 samples, D=4096 statevector dim (fixed by reference)
#define NN 8192
#define DD 4096
#define BK 64           // K-step (one i8 MFMA covers K=64)
#define NT (DD / BK)    // 64 K-steps
#define NBLK 64         // 8192 / 128
#define LDS_T 16384     // one tile: 128 rows x 128 B (re[64]|im[64] i8, 8-slot XOR swizzle)
#define LDSBUF 32768    // A tile + B tile
#define NTILE 2080      // upper-tri incl diagonal: 64*65/2

typedef int   i32x4 __attribute__((ext_vector_type(4)));
typedef float f32x4 __attribute__((ext_vector_type(4)));

#define GLOAD(g, l) __builtin_amdgcn_global_load_lds( \
    (__attribute__((address_space(1))) uint32_t*)(void*)(size_t)(g), \
    (__attribute__((address_space(3))) uint32_t*)(void*)(l), 16, 0, 0)

#define VMW0() asm volatile("s_waitcnt vmcnt(0)" ::: "memory")
#define LGK0() asm volatile("s_waitcnt lgkmcnt(0)" ::: "memory")
#define SBAR() __builtin_amdgcn_s_barrier()

#define MFMA_I8(a, b, c) __builtin_amdgcn_mfma_i32_16x16x64_i8((a), (b), (c), 0, 0, 0)

// fp32 -> per-row-scaled int8 (planar re8/im8 + scales). Verified round 8.
__global__ __launch_bounds__(256) void convert_kernel(
    const float* __restrict__ re, const float* __restrict__ im,
    char* __restrict__ re8, char* __restrict__ im8, float* __restrict__ scales) {
  __shared__ float red[4];
  const int row = blockIdx.x;
  const int t = threadIdx.x;
  const float4* rr = (const float4*)(re + (size_t)row * DD);
  const float4* ir = (const float4*)(im + (size_t)row * DD);
  float4 rv[4], iv[4];
  float mx = 0.f;
#pragma unroll
  for (int c = 0; c < 4; ++c) {
    rv[c] = rr[t * 4 + c];
    iv[c] = ir[t * 4 + c];
    mx = fmaxf(mx, fmaxf(fmaxf(fabsf(rv[c].x), fabsf(rv[c].y)),
                         fmaxf(fabsf(rv[c].z), fabsf(rv[c].w))));
    mx = fmaxf(mx, fmaxf(fmaxf(fabsf(iv[c].x), fabsf(iv[c].y)),
                         fmaxf(fabsf(iv[c].z), fabsf(iv[c].w))));
  }
#pragma unroll
  for (int off = 32; off > 0; off >>= 1) mx = fmaxf(mx, __shfl_down(mx, off));
  if ((t & 63) == 0) red[t >> 6] = mx;
  __syncthreads();
  mx = fmaxf(fmaxf(red[0], red[1]), fmaxf(red[2], red[3]));
  const float inv = (mx > 1e-30f) ? (127.0f / mx) : 0.0f;
  if (t == 0) scales[row] = mx * (1.0f / 127.0f);

  i32x4 rp, ip;
#pragma unroll
  for (int c = 0; c < 4; ++c) {
    int b0 = (int)rintf(rv[c].x * inv), b1 = (int)rintf(rv[c].y * inv);
    int b2 = (int)rintf(rv[c].z * inv), b3 = (int)rintf(rv[c].w * inv);
    rp[c] = (b0 & 0xFF) | ((b1 & 0xFF) << 8) | ((b2 & 0xFF) << 16) | (b3 << 24);
    b0 = (int)rintf(iv[c].x * inv); b1 = (int)rintf(iv[c].y * inv);
    b2 = (int)rintf(iv[c].z * inv); b3 = (int)rintf(iv[c].w * inv);
    ip[c] = (b0 & 0xFF) | ((b1 & 0xFF) << 8) | ((b2 & 0xFF) << 16) | (b3 << 24);
  }
  ((i32x4*)(re8 + (size_t)row * DD))[t] = rp;
  ((i32x4*)(im8 + (size_t)row * DD))[t] = ip;
}

// 128x128 tile of G per block-pair (bi, bj), bi <= bj (round-4 map, verified).
// 4 waves, wave-tile 64x64: 16 LDS reads feed 64 MFMA (256 B/MFMA, vs r8's 384).
// 3 accumulators: g = re.re'+im.im', x = im.re', y = re.im'; fid=(g*s)^2+((x-y)*s)^2.
// Staging/swizzle byte-identical to verified r8 (SQ_LDS_BANK_CONFLICT==0).
// LDS 64 KB dbuf -> 2 blocks/CU; acc 192 VGPR -> 2 waves/SIMD.
__global__ __launch_bounds__(256, 2) void gram_kernel(
    const char* __restrict__ re8, const char* __restrict__ im8,
    const float* __restrict__ scales,
    float* __restrict__ wts, float* __restrict__ fidp) {
  __shared__ alignas(16) char lds[2 * LDSBUF];  // 64 KB

  // XCD-aware bijective swizzle (2080 = 8*260)
  const int b = blockIdx.x;
  const int t = (b & 7) * 260 + (b >> 3);

  // t -> (bi, bj), bi <= bj (verified rounds 1-7)
  int bi = (int)(((float)(2 * NBLK + 1) -
                  sqrtf((float)((2 * NBLK + 1) * (2 * NBLK + 1) - 8 * t))) * 0.5f);
  if (bi < 0) bi = 0;
  if (bi > NBLK - 1) bi = NBLK - 1;
  while (bi > 0 && t < bi * NBLK - bi * (bi - 1) / 2) --bi;
  while (t >= (bi + 1) * NBLK - (bi + 1) * bi / 2) ++bi;
  const int bj = bi + (t - (bi * NBLK - bi * (bi - 1) / 2));

  const int brow = bi * 128, bcol = bj * 128;
  const int tid = threadIdx.x;
  const int lane = tid & 63;
  const int wid = tid >> 6;               // 4 waves
  const int wr = wid >> 1, wc = wid & 1;  // 2x2 wave grid, 64x64 out per wave
  const int t16 = tid * 16;

  // ---- staging source (pre-swizzled; LDS dest linear). Verified r8 pattern:
  // LDS row r (128 B): physical 16B slot p holds logical slot p^(r&7);
  // logical slots 0-3 = re k-chunks (16 i8), 4-7 = im. ----
  const int srow = tid >> 3;                    // 0..31 (rounds add 32)
  const int slog = (tid & 7) ^ (srow & 7);
  const char* smat = (slog < 4) ? re8 : im8;
  const int scol = (slog & 3) * 16;
  const char* spA = smat + (size_t)(brow + srow) * DD + scol;
  const char* spB = smat + (size_t)(bcol + srow) * DD + scol;
  const size_t r32 = (size_t)32 * DD;

#define STAGE_A(s, bf) do { const size_t ko = (size_t)(s) * BK;   \
    char* lb_ = lds + (bf) * LDSBUF + t16;                        \
    GLOAD(spA + ko,           lb_);                               \
    GLOAD(spA + ko + r32,     lb_ + 4096);                        \
    GLOAD(spA + ko + 2 * r32, lb_ + 8192);                        \
    GLOAD(spA + ko + 3 * r32, lb_ + 12288); } while (0)
#define STAGE_B(s, bf) do { const size_t ko = (size_t)(s) * BK;   \
    char* lb_ = lds + (bf) * LDSBUF + LDS_T + t16;                \
    GLOAD(spB + ko,           lb_);                               \
    GLOAD(spB + ko + r32,     lb_ + 4096);                        \
    GLOAD(spB + ko + 2 * r32, lb_ + 8192);                        \
    GLOAD(spB + ko + 3 * r32, lb_ + 12288); } while (0)

  // ---- fragment read offsets (verified: slot_phys = kg ^ (row&7), row&7 = fr&7) ----
  const int fr = lane & 15;
  const int kg = lane >> 4;
  const int reslot = (kg ^ (fr & 7)) << 4;   // re frag byte slot; im = ^64
  const int arow = (wr * 64 + fr) * 128;     // + m*2048 (m=0..3), A region @0
  const int brw  = (wc * 64 + fr) * 128;     // + n*2048 (n=0..3), B region @LDS_T

  i32x4 acc_g[4][4], acc_x[4][4], acc_y[4][4];   // 192 VGPR
#pragma unroll
  for (int m = 0; m < 4; ++m)
#pragma unroll
    for (int n = 0; n < 4; ++n) {
      acc_g[m][n] = (i32x4){0, 0, 0, 0};
      acc_x[m][n] = (i32x4){0, 0, 0, 0};
      acc_y[m][n] = (i32x4){0, 0, 0, 0};
    }

  // ---- prologue ----
  STAGE_A(0, 0); STAGE_B(0, 0);
  VMW0();
  SBAR();

  for (int s = 0; s < NT; ++s) {
    const char* la = lds + (s & 1) * LDSBUF;
    const char* lb = la + LDS_T;
    const int nb = (s & 1) ^ 1;
    const bool pf = (s + 1 < NT);

    if (pf) { STAGE_A(s + 1, nb); STAGE_B(s + 1, nb); }  // 8 loads in flight all step

    i32x4 ar[4], ai[4];
#pragma unroll
    for (int m = 0; m < 4; ++m) {
      ar[m] = *(const i32x4*)(la + arow + m * 2048 + reslot);
      ai[m] = *(const i32x4*)(la + arow + m * 2048 + (reslot ^ 64));
    }
#pragma unroll
    for (int n = 0; n < 4; ++n) {
      i32x4 brf = *(const i32x4*)(lb + brw + n * 2048 + reslot);
      i32x4 bif = *(const i32x4*)(lb + brw + n * 2048 + (reslot ^ 64));
      __builtin_amdgcn_s_setprio(1);
#pragma unroll
      for (int m = 0; m < 4; ++m) {
        acc_g[m][n] = MFMA_I8(ar[m], brf, acc_g[m][n]);
        acc_g[m][n] = MFMA_I8(ai[m], bif, acc_g[m][n]);
        acc_x[m][n] = MFMA_I8(ai[m], brf, acc_x[m][n]);
        acc_y[m][n] = MFMA_I8(ar[m], bif, acc_y[m][n]);
      }
      __builtin_amdgcn_s_setprio(0);
    }

    LGK0();   // own ds_reads done before buffer is re-staged next step
    VMW0();   // staging of s+1 landed (issued a full step earlier)
    SBAR();
  }

  // ---- epilogue: 16x16 C/D layout (verified): col=lane&15, row=(lane>>4)*4+reg ----
  const int grow0 = brow + wr * 64 + kg * 4;  // + m*16 + j
  const int gcol0 = bcol + wc * 64 + fr;      // + n*16

#pragma unroll
  for (int m = 0; m < 4; ++m) {
#pragma unroll
    for (int n = 0; n < 4; ++n) {
      const int gc = gcol0 + n * 16;
      const float sb = scales[gc];
      f32x4 fv;
#pragma unroll
      for (int j = 0; j < 4; ++j) {
        const int grow = grow0 + m * 16 + j;
        const float ss = scales[grow] * sb;
        const float gr = (float)acc_g[m][n][j] * ss;
        const float gi = (float)(acc_x[m][n][j] - acc_y[m][n][j]) * ss;
        fv[j] = gr * gr + gi * gi;
      }
#pragma unroll
      for (int j = 0; j < 4; ++j) {
        const int grow = grow0 + m * 16 + j;
        const float f = fv[j];
        fidp[(size_t)grow * NN + gc] = f;
        float w = 0.0f;
        if (grow < gc) w = (f >= 0.8f) ? 1.0f : ((f >= 0.5f) ? 0.5f : 0.0f);
        wts[(size_t)grow * NN + gc] = w;
      }
      if (bi != bj) {  // fid symmetric: mirror 4 contiguous rows at transposed addr
        *(f32x4*)(fidp + (size_t)gc * NN + grow0 + m * 16) = fv;
      }
    }
  }

  if (bi != bj) {
    // mirror block (bj,bi) of wts is strictly lower-triangular -> zeros
    const f32x4 zz = {0.f, 0.f, 0.f, 0.f};
    for (int i = tid; i < 4096; i += 256) {
      const int r = i >> 5, c4 = i & 31;
      *(f32x4*)(wts + (size_t)(bcol + r) * NN + brow + c4 * 4) = zz;
    }
  }
}

extern "C" void kernel_launch(void* const* d_in, const int* in_sizes, int n_in,
                              void* d_out, int out_size, void* d_ws, size_t ws_size,
                              hipStream_t stream) {
  const float* re = (const float*)d_in[0];
  const float* im = (const float*)d_in[1];
  float* out = (float*)d_out;

  char* re8 = (char*)d_ws;                               // N*D i8
  char* im8 = re8 + (size_t)NN * DD;                     // N*D i8
  float* scales = (float*)(im8 + (size_t)NN * DD);       // N f32  (~67 MB total)

  convert_kernel<<<NN, 256, 0, stream>>>(re, im, re8, im8, scales);
  gram_kernel<<<NTILE, 256, 0, stream>>>(re8, im8, scales, out, out + (size_t)NN * NN);
}